// Round 2
// baseline (58928.668 us; speedup 1.0000x reference)
//
#include <hip/hip_runtime.h>

// Seq2Seq LSTM (2-layer enc 512 steps + 2-layer dec 96 steps), B=512, H=512.
// Persistent kernel, 256 WGs x 256 thr, device-scope grid barrier between
// phases. R2 change: split-bf16 (hi+lo) on BOTH activations and weights,
// 3 MFMAs per product term (ah*wh + ah*wl + al*wh) -> per-product rel err
// ~2^-17 instead of 2^-9. R1 failed with absmax 0.152 (threshold 0.0403),
// pure bf16 compounding over 608 recurrent steps; predicted now ~6e-4.

typedef unsigned int u32;
typedef unsigned short u16;

using bf16x8  = __attribute__((ext_vector_type(8))) __bf16;
using u16x8   = __attribute__((ext_vector_type(8))) u16;
using floatx4 = __attribute__((ext_vector_type(4))) float;

#define NWG 256
#define HB  262144   // 512*512 elements of one h/c plane

// weight plane offsets (hi plane at 0, lo plane at +W_PLANE)
#define ENC0_PLANE ((size_t)2048 * 640)
#define ENC1_PLANE ((size_t)2048 * 1024)
#define DEC0_PLANE ((size_t)2048 * 512)
#define DEC1_PLANE ((size_t)2048 * 1024)

__device__ __forceinline__ u16 f2bf(float f) {
  u32 u = __builtin_bit_cast(u32, f);
  u += 0x7FFFu + ((u >> 16) & 1u);   // RNE
  return (u16)(u >> 16);
}
__device__ __forceinline__ float bf2f(u16 h) {
  return __builtin_bit_cast(float, (u32)h << 16);
}
__device__ __forceinline__ bf16x8 ld8(const u16* p) {
  return __builtin_bit_cast(bf16x8, *reinterpret_cast<const u16x8*>(p));
}
__device__ __forceinline__ float sig_(float x) {
  x = fminf(fmaxf(x, -30.f), 30.f);
  return 1.f / (1.f + __expf(-x));
}
__device__ __forceinline__ float tanh_(float x) {
  x = fminf(fmaxf(x, -15.f), 15.f);
  float e = __expf(2.f * x);
  return (e - 1.f) / (e + 1.f);
}

#define MFMA(a, b, c) __builtin_amdgcn_mfma_f32_16x16x32_bf16((a), (b), (c), 0, 0, 0)

// ---- split GEMM over one K=512 segment: acc[g] += A_tile @ Wseg[g]^T -------
// A: bf16 hi plane, lo plane at +HB. Wseg: hi plane, lo at +wplane.
// Fragment layouts (m89/m120): A[m=lane&15][k=quad*8+j]; B lane=n holds W[n][k].
__device__ __forceinline__ void gemm_seg512s(floatx4* acc,
    const u16* __restrict__ Ahi, const u16* __restrict__ Wseg, size_t wplane,
    int strideW, int row0, int j0, int lane)
{
  const int quad = lane >> 4, l15 = lane & 15;
  const u16* ap = Ahi + ((size_t)(row0 + l15) << 9) + (quad << 3);
  const u16* wp = Wseg + (size_t)(j0 + l15) * strideW + (quad << 3);
  const size_t gs = (size_t)strideW << 9;   // 512 W-rows per gate block
  #pragma unroll 2
  for (int k = 0; k < 512; k += 32) {
    bf16x8 ah = ld8(ap + k);
    bf16x8 al = ld8(ap + k + HB);
    #pragma unroll
    for (int g = 0; g < 4; ++g) {
      bf16x8 wh = ld8(wp + k + g * gs);
      bf16x8 wl = ld8(wp + k + g * gs + wplane);
      acc[g] = MFMA(ah, wh, acc[g]);
      acc[g] = MFMA(ah, wl, acc[g]);
      acc[g] = MFMA(al, wh, acc[g]);
    }
  }
}

// ---- K=128 segment reading X_encode fp32 (B,T,128), split on the fly -------
__device__ __forceinline__ void gemm_x128s(floatx4* acc,
    const float* __restrict__ X, int t,
    const u16* __restrict__ Wseg, size_t wplane, int strideW,
    int row0, int j0, int lane)
{
  const int quad = lane >> 4, l15 = lane & 15;
  const float* xp = X + ((size_t)(row0 + l15) * 512 + t) * 128 + (quad << 3);
  const u16* wp = Wseg + (size_t)(j0 + l15) * strideW + (quad << 3);
  const size_t gs = (size_t)strideW << 9;
  #pragma unroll
  for (int k = 0; k < 128; k += 32) {
    floatx4 xa = *reinterpret_cast<const floatx4*>(xp + k);
    floatx4 xb = *reinterpret_cast<const floatx4*>(xp + k + 4);
    u16x8 uh, ul;
    #pragma unroll
    for (int i = 0; i < 4; ++i) {
      u16 h0 = f2bf(xa[i]); uh[i] = h0;     ul[i] = f2bf(xa[i] - bf2f(h0));
      u16 h1 = f2bf(xb[i]); uh[4 + i] = h1; ul[4 + i] = f2bf(xb[i] - bf2f(h1));
    }
    bf16x8 ah = __builtin_bit_cast(bf16x8, uh);
    bf16x8 al = __builtin_bit_cast(bf16x8, ul);
    #pragma unroll
    for (int g = 0; g < 4; ++g) {
      bf16x8 wh = ld8(wp + k + g * gs);
      bf16x8 wl = ld8(wp + k + g * gs + wplane);
      acc[g] = MFMA(ah, wh, acc[g]);
      acc[g] = MFMA(ah, wl, acc[g]);
      acc[g] = MFMA(al, wh, acc[g]);
    }
  }
}

__device__ __forceinline__ void store_h_split(u16* __restrict__ hout,
                                              size_t off, float h) {
  u16 hh = f2bf(h);
  hout[off] = hh;
  hout[off + HB] = f2bf(h - bf2f(hh));
}

// ---- LSTM cell epilogues (C/D layout: col=lane&15, row=(lane>>4)*4+reg) ----
__device__ __forceinline__ void cell_store(const floatx4* acc,
    float* __restrict__ c, u16* __restrict__ hout,
    const float* __restrict__ bs, int row0, int j0, int lane)
{
  const int quad = lane >> 4, l15 = lane & 15;
  const int col = j0 + l15;
  const float bi = bs[col], bff = bs[512 + col], bg = bs[1024 + col], bo = bs[1536 + col];
  const int r0 = row0 + (quad << 2);
  #pragma unroll
  for (int r = 0; r < 4; ++r) {
    const size_t off = ((size_t)(r0 + r) << 9) + col;
    float ii = sig_(acc[0][r] + bi);
    float ff = sig_(acc[1][r] + bff);
    float gg = tanh_(acc[2][r] + bg);
    float oo = sig_(acc[3][r] + bo);
    float cn = ff * c[off] + ii * gg;
    c[off] = cn;
    store_h_split(hout, off, oo * tanh_(cn));
  }
}

// decoder layer0: adds rank-1 input term inp[b]*W_ih0[j] (fp32, exact)
__device__ __forceinline__ void cell_store_dec0(const floatx4* acc,
    float* __restrict__ c, u16* __restrict__ hout,
    const float* __restrict__ bs, const float* __restrict__ w0col,
    const float* __restrict__ din0, const float* __restrict__ y,
    const int* __restrict__ tfm, const float* __restrict__ dout,
    int t, int row0, int j0, int lane)
{
  const int quad = lane >> 4, l15 = lane & 15;
  const int col = j0 + l15;
  const float bi = bs[col], bff = bs[512 + col], bg = bs[1024 + col], bo = bs[1536 + col];
  const float wi = w0col[col], wf = w0col[512 + col], wg = w0col[1024 + col], wo = w0col[1536 + col];
  const int r0 = row0 + (quad << 2);
  #pragma unroll
  for (int r = 0; r < 4; ++r) {
    const int row = r0 + r;
    float inp;
    if (t == 0) inp = din0[row];
    else inp = (tfm[t - 1] != 0) ? y[row * 96 + t] : dout[row * 96 + (t - 1)];
    const size_t off = ((size_t)row << 9) + col;
    float ii = sig_(acc[0][r] + bi + inp * wi);
    float ff = sig_(acc[1][r] + bff + inp * wf);
    float gg = tanh_(acc[2][r] + bg + inp * wg);
    float oo = sig_(acc[3][r] + bo + inp * wo);
    float cn = ff * c[off] + ii * gg;
    c[off] = cn;
    store_h_split(hout, off, oo * tanh_(cn));
  }
}

// decoder layer1: cell + fc partial dot (shuffle-reduce 16 cols, atomicAdd)
__device__ __forceinline__ void cell_store_dec1(const floatx4* acc,
    float* __restrict__ c, u16* __restrict__ hout,
    const float* __restrict__ bs, const float* __restrict__ fcW,
    const float* __restrict__ fcb, float* __restrict__ dout,
    int t, int row0, int j0, int lane)
{
  const int quad = lane >> 4, l15 = lane & 15;
  const int col = j0 + l15;
  const float bi = bs[col], bff = bs[512 + col], bg = bs[1024 + col], bo = bs[1536 + col];
  const float fw = fcW[col];
  const int r0 = row0 + (quad << 2);
  float s[4];
  #pragma unroll
  for (int r = 0; r < 4; ++r) {
    const size_t off = ((size_t)(r0 + r) << 9) + col;
    float ii = sig_(acc[0][r] + bi);
    float ff = sig_(acc[1][r] + bff);
    float gg = tanh_(acc[2][r] + bg);
    float oo = sig_(acc[3][r] + bo);
    float cn = ff * c[off] + ii * gg;
    c[off] = cn;
    float h = oo * tanh_(cn);
    store_h_split(hout, off, h);
    s[r] = h * fw;
  }
  #pragma unroll
  for (int m = 1; m < 16; m <<= 1) {
    #pragma unroll
    for (int r = 0; r < 4; ++r) s[r] += __shfl_xor(s[r], m, 64);
  }
  if (l15 == 0) {
    #pragma unroll
    for (int r = 0; r < 4; ++r) {
      float v = s[r];
      if (j0 == 0) v += fcb[0];            // exactly one wave per (b,t) adds bias
      atomicAdd(&dout[(size_t)(r0 + r) * 96 + t], v);
    }
  }
}

// ---- persistent kernel -----------------------------------------------------
__global__ __launch_bounds__(256) void seq2seq_persist(
    const float* __restrict__ Xenc, const float* __restrict__ y,
    const int* __restrict__ tfm, const float* __restrict__ dWih0col,
    const float* __restrict__ fcW, const float* __restrict__ fcb,
    const u16* __restrict__ enc0, const u16* __restrict__ enc1,
    const u16* __restrict__ dec0w, const u16* __restrict__ dec1,
    u16* __restrict__ h0bufs, u16* __restrict__ h1bufs,
    float* __restrict__ c0, float* __restrict__ c1,
    const float* __restrict__ bsum, const float* __restrict__ din0,
    float* __restrict__ dout, u32* __restrict__ bar)
{
  const int tid = threadIdx.x;
  const int g = blockIdx.x;
  const int wave = tid >> 6, lane = tid & 63;
  // XCD-aware swizzle: WGs sharing a W-slab (same hj_tile) land on one XCD
  const int q = g >> 3;
  const int hj_tile = (g & 7) + ((q & 1) << 3);  // 0..15
  const int b_tile = q >> 1;                     // 0..15
  const int b0 = b_tile << 5, hj0 = hj_tile << 5;
  const int row0 = b0 + ((wave & 1) << 4);       // 16 batch rows for this wave
  const int j0 = hj0 + ((wave >> 1) << 4);       // 16 h-cols for this wave
  // h buffers: [buf][{hi,lo}] -> buf i at i*2*HB, lo plane at +HB
  u16* h0buf[2] = { h0bufs, h0bufs + 2 * HB };
  u16* h1buf[2] = { h1bufs, h1bufs + 2 * HB };
  unsigned ep = 0;

  auto gbar = [&]() {
    __syncthreads();
    ++ep;
    if (tid == 0) {
      __threadfence();                                   // publish (cross-XCD)
      u32 prev = __hip_atomic_fetch_add(&bar[0], 1u, __ATOMIC_RELAXED, __HIP_MEMORY_SCOPE_AGENT);
      if (prev == NWG - 1) {
        __hip_atomic_store(&bar[0], 0u, __ATOMIC_RELAXED, __HIP_MEMORY_SCOPE_AGENT);
        __threadfence();
        __hip_atomic_store(&bar[1], ep, __ATOMIC_RELAXED, __HIP_MEMORY_SCOPE_AGENT);
      } else {
        while (__hip_atomic_load(&bar[1], __ATOMIC_RELAXED, __HIP_MEMORY_SCOPE_AGENT) < ep)
          __builtin_amdgcn_s_sleep(2);
      }
      __threadfence();                                   // acquire
    }
    __syncthreads();
  };

  // ---------------- encoder: phase p does layer1[p-1] and layer0[p] ----------
  for (int p = 0; p <= 512; ++p) {
    const int cur = p & 1, nxt = cur ^ 1;
    if (p >= 1) {  // layer1[t=p-1]: [h0[t], h1[t-1]] @ enc1_cat^T
      floatx4 acc[4] = { floatx4{0,0,0,0}, floatx4{0,0,0,0}, floatx4{0,0,0,0}, floatx4{0,0,0,0} };
      gemm_seg512s(acc, h0buf[cur], enc1,       ENC1_PLANE, 1024, row0, j0, lane);
      gemm_seg512s(acc, h1buf[cur], enc1 + 512, ENC1_PLANE, 1024, row0, j0, lane);
      cell_store(acc, c1, h1buf[nxt], bsum + 2048, row0, j0, lane);
    }
    if (p <= 511) {  // layer0[t=p]: [x_t, h0[t-1]] @ enc0_cat^T
      floatx4 acc[4] = { floatx4{0,0,0,0}, floatx4{0,0,0,0}, floatx4{0,0,0,0}, floatx4{0,0,0,0} };
      gemm_x128s(acc, Xenc, p, enc0, ENC0_PLANE, 640, row0, j0, lane);
      gemm_seg512s(acc, h0buf[cur], enc0 + 128, ENC0_PLANE, 640, row0, j0, lane);
      cell_store(acc, c0, h0buf[nxt], bsum, row0, j0, lane);
    }
    gbar();
  }

  // ---------------- decoder: 2 phases per step -------------------------------
  int cur0 = 0, cur1 = 1;  // h0[511] in buf0, h1[511] in buf1
  for (int t = 0; t < 96; ++t) {
    {  // layer0[t]: h0 @ dec_W_hh0^T + inp*W_ih0 (rank-1 in epilogue)
      floatx4 acc[4] = { floatx4{0,0,0,0}, floatx4{0,0,0,0}, floatx4{0,0,0,0}, floatx4{0,0,0,0} };
      gemm_seg512s(acc, h0buf[cur0], dec0w, DEC0_PLANE, 512, row0, j0, lane);
      cell_store_dec0(acc, c0, h0buf[cur0 ^ 1], bsum + 4096, dWih0col,
                      din0, y, tfm, dout, t, row0, j0, lane);
    }
    gbar();
    cur0 ^= 1;
    {  // layer1[t]: [h0'[t], h1[t-1]] @ dec1_cat^T, + fc into d_out
      floatx4 acc[4] = { floatx4{0,0,0,0}, floatx4{0,0,0,0}, floatx4{0,0,0,0}, floatx4{0,0,0,0} };
      gemm_seg512s(acc, h0buf[cur0], dec1,       DEC1_PLANE, 1024, row0, j0, lane);
      gemm_seg512s(acc, h1buf[cur1], dec1 + 512, DEC1_PLANE, 1024, row0, j0, lane);
      cell_store_dec1(acc, c1, h1buf[cur1 ^ 1], bsum + 6144, fcW, fcb,
                      dout, t, row0, j0, lane);
    }
    gbar();
    cur1 ^= 1;
  }
}

// ---- prep kernels ----------------------------------------------------------
__global__ void prep_misc(float* c0, float* c1, u16* h0b, u16* h1b,
    float* dout, u32* bar, float* bsum,
    const float* ebih0, const float* ebhh0, const float* ebih1, const float* ebhh1,
    const float* dbih0, const float* dbhh0, const float* dbih1, const float* dbhh1,
    const float* Xdec, float* din0)
{
  const int idx = blockIdx.x * 256 + threadIdx.x;   // grid covers exactly 262144
  c0[idx] = 0.f; c1[idx] = 0.f;
  h0b[idx] = 0; h0b[idx + HB] = 0; h0b[idx + 2 * HB] = 0; h0b[idx + 3 * HB] = 0;
  h1b[idx] = 0; h1b[idx + HB] = 0; h1b[idx + 2 * HB] = 0; h1b[idx + 3 * HB] = 0;
  if (idx < 49152) dout[idx] = 0.f;
  if (idx < 8192) {
    const int which = idx >> 11, j = idx & 2047;
    float v;
    if (which == 0)      v = ebih0[j] + ebhh0[j];
    else if (which == 1) v = ebih1[j] + ebhh1[j];
    else if (which == 2) v = dbih0[j] + dbhh0[j];
    else                 v = dbih1[j] + dbhh1[j];
    bsum[idx] = v;
  }
  if (idx < 512) {   // dec_in0[b] = sum(X_decode[b,:,:])
    float s = 0.f;
    const float* p = Xdec + (size_t)idx * 768;
    for (int i = 0; i < 768; ++i) s += p[i];
    din0[idx] = s;
  }
  if (idx < 2) bar[idx] = 0u;
}

__device__ __forceinline__ void wsplit(u16* dst, size_t plane, size_t i, float w) {
  u16 hh = f2bf(w);
  dst[i] = hh;
  dst[i + plane] = f2bf(w - bf2f(hh));
}

__global__ void prep_weights(u16* enc0, const float* eWih0, const float* eWhh0,
    u16* enc1, const float* eWih1, const float* eWhh1,
    u16* dec0, const float* dWhh0,
    u16* dec1, const float* dWih1, const float* dWhh1)
{
  const int idx = blockIdx.x * 256 + threadIdx.x;   // grid covers 2097152
  if (idx < 2048 * 640) {
    const int j = idx / 640, k = idx - j * 640;
    wsplit(enc0, ENC0_PLANE, idx,
           k < 128 ? eWih0[j * 128 + k] : eWhh0[j * 512 + (k - 128)]);
  }
  {
    const int j = idx >> 10, k = idx & 1023;
    wsplit(enc1, ENC1_PLANE, idx,
           k < 512 ? eWih1[(j << 9) + k] : eWhh1[(j << 9) + k - 512]);
    wsplit(dec1, DEC1_PLANE, idx,
           k < 512 ? dWih1[(j << 9) + k] : dWhh1[(j << 9) + k - 512]);
  }
  if (idx < 2048 * 512) wsplit(dec0, DEC0_PLANE, idx, dWhh0[idx]);
}

// ---- launch ----------------------------------------------------------------
extern "C" void kernel_launch(void* const* d_in, const int* in_sizes, int n_in,
                              void* d_out, int out_size, void* d_ws, size_t ws_size,
                              hipStream_t stream)
{
  const float* Xenc  = (const float*)d_in[0];
  const float* Xdec  = (const float*)d_in[1];
  const float* y     = (const float*)d_in[2];
  const int*   tfm   = (const int*)d_in[3];
  const float* eWih0 = (const float*)d_in[4];
  const float* eWhh0 = (const float*)d_in[5];
  const float* ebih0 = (const float*)d_in[6];
  const float* ebhh0 = (const float*)d_in[7];
  const float* eWih1 = (const float*)d_in[8];
  const float* eWhh1 = (const float*)d_in[9];
  const float* ebih1 = (const float*)d_in[10];
  const float* ebhh1 = (const float*)d_in[11];
  const float* dWih0 = (const float*)d_in[12];
  const float* dWhh0 = (const float*)d_in[13];
  const float* dbih0 = (const float*)d_in[14];
  const float* dbhh0 = (const float*)d_in[15];
  const float* dWih1 = (const float*)d_in[16];
  const float* dWhh1 = (const float*)d_in[17];
  const float* dbih1 = (const float*)d_in[18];
  const float* dbhh1 = (const float*)d_in[19];
  const float* fcW   = (const float*)d_in[20];
  const float* fcb   = (const float*)d_in[21];
  float* dout = (float*)d_out;

  char* base = (char*)d_ws;
  size_t off = 0;
  auto alloc = [&](size_t n) -> char* {
    char* p = base + off;
    off = (off + n + 255) & ~(size_t)255;
    return p;
  };
  u32* bar  = (u32*)alloc(8);
  u16* enc0 = (u16*)alloc(ENC0_PLANE * 2 * 2);   // hi+lo planes
  u16* enc1 = (u16*)alloc(ENC1_PLANE * 2 * 2);
  u16* dec0 = (u16*)alloc(DEC0_PLANE * 2 * 2);
  u16* dec1 = (u16*)alloc(DEC1_PLANE * 2 * 2);
  u16* h0b  = (u16*)alloc((size_t)4 * HB * 2);   // 2 bufs x {hi,lo}
  u16* h1b  = (u16*)alloc((size_t)4 * HB * 2);
  float* c0 = (float*)alloc((size_t)HB * 4);
  float* c1 = (float*)alloc((size_t)HB * 4);
  float* bs = (float*)alloc((size_t)8192 * 4);
  float* di = (float*)alloc((size_t)512 * 4);

  prep_misc<<<1024, 256, 0, stream>>>(c0, c1, h0b, h1b, dout, bar, bs,
      ebih0, ebhh0, ebih1, ebhh1, dbih0, dbhh0, dbih1, dbhh1, Xdec, di);
  prep_weights<<<8192, 256, 0, stream>>>(enc0, eWih0, eWhh0, enc1, eWih1, eWhh1,
      dec0, dWhh0, dec1, dWih1, dWhh1);
  seq2seq_persist<<<NWG, 256, 0, stream>>>(Xenc, y, tfm, dWih0, fcW, fcb,
      enc0, enc1, dec0, dec1, h0b, h1b, c0, c1, bs, di, dout, bar);
}

// Round 4
// 44888.092 us; speedup vs baseline: 1.3128x; 1.3128x over previous
//
#include <hip/hip_runtime.h>

// Seq2Seq LSTM (2-layer enc 512 steps + 2-layer dec 96 steps), B=512, H=512.
// Persistent kernel, 256 WGs x 512 thr (8 waves/CU), split-bf16 (hi+lo) MFMA.
// R4 (= R3 with pragma syntax fixed): fence-free coherence — h/dout cross-WG
// data moves via agent-scope relaxed atomics (LLC-coherent); weights/X/c stay
// L2-resident (no buffer_inv anywhere). Two-level relaxed barrier with
// monotonic epochs. Waves split K 2-way, partials reduced through LDS;
// khalf0 waves do the epilogues.

typedef unsigned int u32;
typedef unsigned short u16;

using bf16x8  = __attribute__((ext_vector_type(8))) __bf16;
using u16x8   = __attribute__((ext_vector_type(8))) u16;
using floatx4 = __attribute__((ext_vector_type(4))) float;

#define NWG 256
#define HB  262144   // 512*512 elements of one h/c plane

#define ENC0_PLANE ((size_t)2048 * 640)
#define ENC1_PLANE ((size_t)2048 * 1024)
#define DEC0_PLANE ((size_t)2048 * 512)
#define DEC1_PLANE ((size_t)2048 * 1024)

__device__ __forceinline__ u16 f2bf(float f) {
  u32 u = __builtin_bit_cast(u32, f);
  u += 0x7FFFu + ((u >> 16) & 1u);   // RNE
  return (u16)(u >> 16);
}
__device__ __forceinline__ float bf2f(u16 h) {
  return __builtin_bit_cast(float, (u32)h << 16);
}
__device__ __forceinline__ bf16x8 ld8(const u16* p) {           // cached (L1/L2)
  return __builtin_bit_cast(bf16x8, *reinterpret_cast<const u16x8*>(p));
}
__device__ __forceinline__ bf16x8 ld8_llc(const u16* p) {       // LLC-coherent
  union { unsigned long long q[2]; bf16x8 v; } cv;
  cv.q[0] = __hip_atomic_load((const unsigned long long*)p,
                              __ATOMIC_RELAXED, __HIP_MEMORY_SCOPE_AGENT);
  cv.q[1] = __hip_atomic_load((const unsigned long long*)(p + 4),
                              __ATOMIC_RELAXED, __HIP_MEMORY_SCOPE_AGENT);
  return cv.v;
}
__device__ __forceinline__ float sig_(float x) {
  x = fminf(fmaxf(x, -30.f), 30.f);
  return 1.f / (1.f + __expf(-x));
}
__device__ __forceinline__ float tanh_(float x) {
  x = fminf(fmaxf(x, -15.f), 15.f);
  float e = __expf(2.f * x);
  return (e - 1.f) / (e + 1.f);
}

#define MFMA(a, b, c) __builtin_amdgcn_mfma_f32_16x16x32_bf16((a), (b), (c), 0, 0, 0)

// ---- split GEMM, K range [kbeg,kend): acc[g] += A @ Wseg[g]^T --------------
// A hi plane + lo at +HB (LLC loads). W hi plane + lo at +wplane (cached).
__device__ __forceinline__ void gemm_seg(floatx4* acc,
    const u16* __restrict__ Ahi, const u16* __restrict__ Wseg, size_t wplane,
    int strideW, int row0, int j0, int lane, int kbeg, int kend)
{
  const int quad = lane >> 4, l15 = lane & 15;
  const u16* ap = Ahi + ((size_t)(row0 + l15) << 9) + (quad << 3);
  const u16* wp = Wseg + (size_t)(j0 + l15) * strideW + (quad << 3);
  const size_t gs = (size_t)strideW << 9;   // 512 W-rows per gate block
  #pragma unroll 2
  for (int k = kbeg; k < kend; k += 32) {
    bf16x8 ah = ld8_llc(ap + k);
    bf16x8 al = ld8_llc(ap + k + HB);
    #pragma unroll
    for (int g = 0; g < 4; ++g) {
      bf16x8 wh = ld8(wp + k + g * gs);
      bf16x8 wl = ld8(wp + k + g * gs + wplane);
      acc[g] = MFMA(ah, wh, acc[g]);
      acc[g] = MFMA(ah, wl, acc[g]);
      acc[g] = MFMA(al, wh, acc[g]);
    }
  }
}

// ---- K=128 segment reading X_encode fp32 (B,T,128), split on the fly -------
__device__ __forceinline__ void gemm_x128s(floatx4* acc,
    const float* __restrict__ X, int t,
    const u16* __restrict__ Wseg, size_t wplane, int strideW,
    int row0, int j0, int lane)
{
  const int quad = lane >> 4, l15 = lane & 15;
  const float* xp = X + ((size_t)(row0 + l15) * 512 + t) * 128 + (quad << 3);
  const u16* wp = Wseg + (size_t)(j0 + l15) * strideW + (quad << 3);
  const size_t gs = (size_t)strideW << 9;
  #pragma unroll
  for (int k = 0; k < 128; k += 32) {
    floatx4 xa = *reinterpret_cast<const floatx4*>(xp + k);
    floatx4 xb = *reinterpret_cast<const floatx4*>(xp + k + 4);
    u16x8 uh, ul;
    #pragma unroll
    for (int i = 0; i < 4; ++i) {
      u16 h0 = f2bf(xa[i]); uh[i] = h0;     ul[i] = f2bf(xa[i] - bf2f(h0));
      u16 h1 = f2bf(xb[i]); uh[4 + i] = h1; ul[4 + i] = f2bf(xb[i] - bf2f(h1));
    }
    bf16x8 ah = __builtin_bit_cast(bf16x8, uh);
    bf16x8 al = __builtin_bit_cast(bf16x8, ul);
    #pragma unroll
    for (int g = 0; g < 4; ++g) {
      bf16x8 wh = ld8(wp + k + g * gs);
      bf16x8 wl = ld8(wp + k + g * gs + wplane);
      acc[g] = MFMA(ah, wh, acc[g]);
      acc[g] = MFMA(ah, wl, acc[g]);
      acc[g] = MFMA(al, wh, acc[g]);
    }
  }
}

__device__ __forceinline__ void store_h_split(u16* __restrict__ hout,
                                              size_t off, float h) {
  u16 hh = f2bf(h);
  u16 hl = f2bf(h - bf2f(hh));
  __hip_atomic_store(hout + off,      hh, __ATOMIC_RELAXED, __HIP_MEMORY_SCOPE_AGENT);
  __hip_atomic_store(hout + off + HB, hl, __ATOMIC_RELAXED, __HIP_MEMORY_SCOPE_AGENT);
}

// ---- LSTM cell epilogues (C/D layout: col=lane&15, row=(lane>>4)*4+reg) ----
__device__ __forceinline__ void cell_store(const floatx4* acc,
    float* __restrict__ c, u16* __restrict__ hout,
    const float* __restrict__ bs, int row0, int j0, int lane)
{
  const int quad = lane >> 4, l15 = lane & 15;
  const int col = j0 + l15;
  const float bi = bs[col], bff = bs[512 + col], bg = bs[1024 + col], bo = bs[1536 + col];
  const int r0 = row0 + (quad << 2);
  #pragma unroll
  for (int r = 0; r < 4; ++r) {
    const size_t off = ((size_t)(r0 + r) << 9) + col;
    float ii = sig_(acc[0][r] + bi);
    float ff = sig_(acc[1][r] + bff);
    float gg = tanh_(acc[2][r] + bg);
    float oo = sig_(acc[3][r] + bo);
    float cn = ff * c[off] + ii * gg;
    c[off] = cn;
    store_h_split(hout, off, oo * tanh_(cn));
  }
}

// decoder layer0: adds rank-1 input term inp[b]*W_ih0[j] (fp32, exact)
__device__ __forceinline__ void cell_store_dec0(const floatx4* acc,
    float* __restrict__ c, u16* __restrict__ hout,
    const float* __restrict__ bs, const float* __restrict__ w0col,
    const float* __restrict__ din0, const float* __restrict__ y,
    const int* __restrict__ tfm, float* __restrict__ dout,
    int t, int row0, int j0, int lane)
{
  const int quad = lane >> 4, l15 = lane & 15;
  const int col = j0 + l15;
  const float bi = bs[col], bff = bs[512 + col], bg = bs[1024 + col], bo = bs[1536 + col];
  const float wi = w0col[col], wf = w0col[512 + col], wg = w0col[1024 + col], wo = w0col[1536 + col];
  const int r0 = row0 + (quad << 2);
  #pragma unroll
  for (int r = 0; r < 4; ++r) {
    const int row = r0 + r;
    float inp;
    if (t == 0) inp = din0[row];
    else if (tfm[t - 1] != 0) inp = y[row * 96 + t];
    else inp = __hip_atomic_load(dout + row * 96 + (t - 1),
                                 __ATOMIC_RELAXED, __HIP_MEMORY_SCOPE_AGENT);
    const size_t off = ((size_t)row << 9) + col;
    float ii = sig_(acc[0][r] + bi + inp * wi);
    float ff = sig_(acc[1][r] + bff + inp * wf);
    float gg = tanh_(acc[2][r] + bg + inp * wg);
    float oo = sig_(acc[3][r] + bo + inp * wo);
    float cn = ff * c[off] + ii * gg;
    c[off] = cn;
    store_h_split(hout, off, oo * tanh_(cn));
  }
}

// decoder layer1: cell + fc partial dot (shuffle-reduce 16 cols, atomicAdd)
__device__ __forceinline__ void cell_store_dec1(const floatx4* acc,
    float* __restrict__ c, u16* __restrict__ hout,
    const float* __restrict__ bs, const float* __restrict__ fcW,
    const float* __restrict__ fcb, float* __restrict__ dout,
    int t, int row0, int j0, int lane)
{
  const int quad = lane >> 4, l15 = lane & 15;
  const int col = j0 + l15;
  const float bi = bs[col], bff = bs[512 + col], bg = bs[1024 + col], bo = bs[1536 + col];
  const float fw = fcW[col];
  const int r0 = row0 + (quad << 2);
  float s[4];
  #pragma unroll
  for (int r = 0; r < 4; ++r) {
    const size_t off = ((size_t)(r0 + r) << 9) + col;
    float ii = sig_(acc[0][r] + bi);
    float ff = sig_(acc[1][r] + bff);
    float gg = tanh_(acc[2][r] + bg);
    float oo = sig_(acc[3][r] + bo);
    float cn = ff * c[off] + ii * gg;
    c[off] = cn;
    float h = oo * tanh_(cn);
    store_h_split(hout, off, h);
    s[r] = h * fw;
  }
  #pragma unroll
  for (int m = 1; m < 16; m <<= 1) {
    #pragma unroll
    for (int r = 0; r < 4; ++r) s[r] += __shfl_xor(s[r], m, 64);
  }
  if (l15 == 0) {
    #pragma unroll
    for (int r = 0; r < 4; ++r) {
      float v = s[r];
      if (j0 == 0) v += fcb[0];            // exactly one wave per (b,t) adds bias
      atomicAdd(&dout[(size_t)(r0 + r) * 96 + t], v);
    }
  }
}

// ---- persistent kernel -----------------------------------------------------
__global__ __launch_bounds__(512) void seq2seq_persist(
    const float* __restrict__ Xenc, const float* __restrict__ y,
    const int* __restrict__ tfm, const float* __restrict__ dWih0col,
    const float* __restrict__ fcW, const float* __restrict__ fcb,
    const u16* __restrict__ enc0, const u16* __restrict__ enc1,
    const u16* __restrict__ dec0w, const u16* __restrict__ dec1,
    u16* __restrict__ h0bufs, u16* __restrict__ h1bufs,
    float* __restrict__ c0, float* __restrict__ c1,
    const float* __restrict__ bsum, const float* __restrict__ din0,
    float* __restrict__ dout, u32* __restrict__ bar)
{
  const int tid = threadIdx.x;
  const int g = blockIdx.x;
  const int wave = tid >> 6, lane = tid & 63;
  const int w4 = wave & 3, kh = wave >> 2;      // tile-quadrant, K-half
  // XCD-aware swizzle: WGs sharing a W-slab (same hj_tile) land on one XCD
  const int q = g >> 3;
  const int hj_tile = (g & 7) + ((q & 1) << 3);  // 0..15
  const int b_tile = q >> 1;                     // 0..15
  const int b0 = b_tile << 5, hj0 = hj_tile << 5;
  const int row0 = b0 + ((w4 & 1) << 4);         // 16 batch rows
  const int j0 = hj0 + ((w4 >> 1) << 4);         // 16 h-cols
  const int slot = g & 7;
  u16* h0buf[2] = { h0bufs, h0bufs + 2 * HB };
  u16* h1buf[2] = { h1bufs, h1bufs + 2 * HB };
  unsigned ep = 0;

  __shared__ floatx4 xb[2048];   // 8 regions x 4 gates x 64 lanes = 32 KB
  #define XR(w4_, L_, g_) (((((w4_) * 2 + (L_)) * 4 + (g_)) << 6) + lane)

  // fence-free barrier: monotonic relaxed counters; data moves via LLC.
  auto gbar = [&]() {
    __syncthreads();
    ++ep;
    if (tid == 0) {
      u32 prev = __hip_atomic_fetch_add(&bar[slot * 32], 1u,
                     __ATOMIC_RELAXED, __HIP_MEMORY_SCOPE_AGENT);
      if (prev == ep * 32u - 1u) {
        u32 pm = __hip_atomic_fetch_add(&bar[256], 1u,
                     __ATOMIC_RELAXED, __HIP_MEMORY_SCOPE_AGENT);
        if (pm == ep * 8u - 1u)
          __hip_atomic_store(&bar[288], ep,
                     __ATOMIC_RELAXED, __HIP_MEMORY_SCOPE_AGENT);
      }
      while (__hip_atomic_load(&bar[288],
                 __ATOMIC_RELAXED, __HIP_MEMORY_SCOPE_AGENT) < ep)
        __builtin_amdgcn_s_sleep(1);
    }
    asm volatile("" ::: "memory");
    __syncthreads();
  };

  // ---------------- encoder: phase p does layer1[p-1] and layer0[p] ----------
  for (int p = 0; p <= 512; ++p) {
    const int cur = p & 1, nxt = cur ^ 1;
    floatx4 a1[4] = { floatx4{0,0,0,0}, floatx4{0,0,0,0}, floatx4{0,0,0,0}, floatx4{0,0,0,0} };
    floatx4 a0[4] = { floatx4{0,0,0,0}, floatx4{0,0,0,0}, floatx4{0,0,0,0}, floatx4{0,0,0,0} };
    if (p >= 1) {  // layer1[t=p-1]: [h0[t], h1[t-1]] @ enc1_cat^T
      if (kh == 0) {
        gemm_seg(a1, h0buf[cur], enc1,       ENC1_PLANE, 1024, row0, j0, lane, 0, 256);
        gemm_seg(a1, h1buf[cur], enc1 + 512, ENC1_PLANE, 1024, row0, j0, lane, 0, 256);
      } else {
        gemm_seg(a1, h0buf[cur], enc1,       ENC1_PLANE, 1024, row0, j0, lane, 256, 512);
        gemm_seg(a1, h1buf[cur], enc1 + 512, ENC1_PLANE, 1024, row0, j0, lane, 256, 512);
      }
    }
    if (p <= 511) {  // layer0[t=p]: [x_t, h0[t-1]] @ enc0_cat^T
      if (kh == 0) {
        gemm_x128s(a0, Xenc, p, enc0, ENC0_PLANE, 640, row0, j0, lane);
        gemm_seg(a0, h0buf[cur], enc0 + 128, ENC0_PLANE, 640, row0, j0, lane, 0, 192);
      } else {
        gemm_seg(a0, h0buf[cur], enc0 + 128, ENC0_PLANE, 640, row0, j0, lane, 192, 512);
      }
    }
    __syncthreads();
    if (kh == 1) {
      if (p >= 1) {
        for (int gg = 0; gg < 4; ++gg) xb[XR(w4, 0, gg)] = a1[gg];
      }
      if (p <= 511) {
        for (int gg = 0; gg < 4; ++gg) xb[XR(w4, 1, gg)] = a0[gg];
      }
    }
    __syncthreads();
    if (kh == 0) {
      if (p >= 1) {
        for (int gg = 0; gg < 4; ++gg) a1[gg] += xb[XR(w4, 0, gg)];
        cell_store(a1, c1, h1buf[nxt], bsum + 2048, row0, j0, lane);
      }
      if (p <= 511) {
        for (int gg = 0; gg < 4; ++gg) a0[gg] += xb[XR(w4, 1, gg)];
        cell_store(a0, c0, h0buf[nxt], bsum, row0, j0, lane);
      }
    }
    gbar();
  }

  // ---------------- decoder: 2 phases per step -------------------------------
  int cur0 = 0, cur1 = 1;  // h0[511] in buf0, h1[511] in buf1
  for (int t = 0; t < 96; ++t) {
    {  // layer0[t]: h0 @ dec_W_hh0^T + inp*W_ih0 (rank-1 in epilogue)
      floatx4 acc[4] = { floatx4{0,0,0,0}, floatx4{0,0,0,0}, floatx4{0,0,0,0}, floatx4{0,0,0,0} };
      if (kh == 0) gemm_seg(acc, h0buf[cur0], dec0w, DEC0_PLANE, 512, row0, j0, lane, 0, 256);
      else         gemm_seg(acc, h0buf[cur0], dec0w, DEC0_PLANE, 512, row0, j0, lane, 256, 512);
      __syncthreads();
      if (kh == 1) {
        for (int gg = 0; gg < 4; ++gg) xb[XR(w4, 0, gg)] = acc[gg];
      }
      __syncthreads();
      if (kh == 0) {
        for (int gg = 0; gg < 4; ++gg) acc[gg] += xb[XR(w4, 0, gg)];
        cell_store_dec0(acc, c0, h0buf[cur0 ^ 1], bsum + 4096, dWih0col,
                        din0, y, tfm, dout, t, row0, j0, lane);
      }
    }
    gbar();
    cur0 ^= 1;
    {  // layer1[t]: [h0'[t], h1[t-1]] @ dec1_cat^T, + fc into d_out
      floatx4 acc[4] = { floatx4{0,0,0,0}, floatx4{0,0,0,0}, floatx4{0,0,0,0}, floatx4{0,0,0,0} };
      if (kh == 0) {
        gemm_seg(acc, h0buf[cur0], dec1,       DEC1_PLANE, 1024, row0, j0, lane, 0, 256);
        gemm_seg(acc, h1buf[cur1], dec1 + 512, DEC1_PLANE, 1024, row0, j0, lane, 0, 256);
      } else {
        gemm_seg(acc, h0buf[cur0], dec1,       DEC1_PLANE, 1024, row0, j0, lane, 256, 512);
        gemm_seg(acc, h1buf[cur1], dec1 + 512, DEC1_PLANE, 1024, row0, j0, lane, 256, 512);
      }
      __syncthreads();
      if (kh == 1) {
        for (int gg = 0; gg < 4; ++gg) xb[XR(w4, 0, gg)] = acc[gg];
      }
      __syncthreads();
      if (kh == 0) {
        for (int gg = 0; gg < 4; ++gg) acc[gg] += xb[XR(w4, 0, gg)];
        cell_store_dec1(acc, c1, h1buf[cur1 ^ 1], bsum + 6144, fcW, fcb,
                        dout, t, row0, j0, lane);
      }
    }
    gbar();
    cur1 ^= 1;
  }
}

// ---- prep kernels ----------------------------------------------------------
__global__ void prep_misc(float* c0, float* c1, u16* h0b, u16* h1b,
    float* dout, u32* bar, float* bsum,
    const float* ebih0, const float* ebhh0, const float* ebih1, const float* ebhh1,
    const float* dbih0, const float* dbhh0, const float* dbih1, const float* dbhh1,
    const float* Xdec, float* din0)
{
  const int idx = blockIdx.x * 256 + threadIdx.x;   // grid covers exactly 262144
  c0[idx] = 0.f; c1[idx] = 0.f;
  h0b[idx] = 0; h0b[idx + HB] = 0; h0b[idx + 2 * HB] = 0; h0b[idx + 3 * HB] = 0;
  h1b[idx] = 0; h1b[idx + HB] = 0; h1b[idx + 2 * HB] = 0; h1b[idx + 3 * HB] = 0;
  if (idx < 49152) dout[idx] = 0.f;
  if (idx < 8192) {
    const int which = idx >> 11, j = idx & 2047;
    float v;
    if (which == 0)      v = ebih0[j] + ebhh0[j];
    else if (which == 1) v = ebih1[j] + ebhh1[j];
    else if (which == 2) v = dbih0[j] + dbhh0[j];
    else                 v = dbih1[j] + dbhh1[j];
    bsum[idx] = v;
  }
  if (idx < 512) {   // dec_in0[b] = sum(X_decode[b,:,:])
    float s = 0.f;
    const float* p = Xdec + (size_t)idx * 768;
    for (int i = 0; i < 768; ++i) s += p[i];
    din0[idx] = s;
  }
  if (idx < 320) bar[idx] = 0u;
}

__device__ __forceinline__ void wsplit(u16* dst, size_t plane, size_t i, float w) {
  u16 hh = f2bf(w);
  dst[i] = hh;
  dst[i + plane] = f2bf(w - bf2f(hh));
}

__global__ void prep_weights(u16* enc0, const float* eWih0, const float* eWhh0,
    u16* enc1, const float* eWih1, const float* eWhh1,
    u16* dec0, const float* dWhh0,
    u16* dec1, const float* dWih1, const float* dWhh1)
{
  const int idx = blockIdx.x * 256 + threadIdx.x;   // grid covers 2097152
  if (idx < 2048 * 640) {
    const int j = idx / 640, k = idx - j * 640;
    wsplit(enc0, ENC0_PLANE, idx,
           k < 128 ? eWih0[j * 128 + k] : eWhh0[j * 512 + (k - 128)]);
  }
  {
    const int j = idx >> 10, k = idx & 1023;
    wsplit(enc1, ENC1_PLANE, idx,
           k < 512 ? eWih1[(j << 9) + k] : eWhh1[(j << 9) + k - 512]);
    wsplit(dec1, DEC1_PLANE, idx,
           k < 512 ? dWih1[(j << 9) + k] : dWhh1[(j << 9) + k - 512]);
  }
  if (idx < 2048 * 512) wsplit(dec0, DEC0_PLANE, idx, dWhh0[idx]);
}

// ---- launch ----------------------------------------------------------------
extern "C" void kernel_launch(void* const* d_in, const int* in_sizes, int n_in,
                              void* d_out, int out_size, void* d_ws, size_t ws_size,
                              hipStream_t stream)
{
  const float* Xenc  = (const float*)d_in[0];
  const float* Xdec  = (const float*)d_in[1];
  const float* y     = (const float*)d_in[2];
  const int*   tfm   = (const int*)d_in[3];
  const float* eWih0 = (const float*)d_in[4];
  const float* eWhh0 = (const float*)d_in[5];
  const float* ebih0 = (const float*)d_in[6];
  const float* ebhh0 = (const float*)d_in[7];
  const float* eWih1 = (const float*)d_in[8];
  const float* eWhh1 = (const float*)d_in[9];
  const float* ebih1 = (const float*)d_in[10];
  const float* ebhh1 = (const float*)d_in[11];
  const float* dWih0 = (const float*)d_in[12];
  const float* dWhh0 = (const float*)d_in[13];
  const float* dbih0 = (const float*)d_in[14];
  const float* dbhh0 = (const float*)d_in[15];
  const float* dWih1 = (const float*)d_in[16];
  const float* dWhh1 = (const float*)d_in[17];
  const float* dbih1 = (const float*)d_in[18];
  const float* dbhh1 = (const float*)d_in[19];
  const float* fcW   = (const float*)d_in[20];
  const float* fcb   = (const float*)d_in[21];
  float* dout = (float*)d_out;

  char* base = (char*)d_ws;
  size_t off = 0;
  auto alloc = [&](size_t n) -> char* {
    char* p = base + off;
    off = (off + n + 255) & ~(size_t)255;
    return p;
  };
  u32* bar  = (u32*)alloc(320 * 4);
  u16* enc0 = (u16*)alloc(ENC0_PLANE * 2 * 2);   // hi+lo planes
  u16* enc1 = (u16*)alloc(ENC1_PLANE * 2 * 2);
  u16* dec0 = (u16*)alloc(DEC0_PLANE * 2 * 2);
  u16* dec1 = (u16*)alloc(DEC1_PLANE * 2 * 2);
  u16* h0b  = (u16*)alloc((size_t)4 * HB * 2);   // 2 bufs x {hi,lo}
  u16* h1b  = (u16*)alloc((size_t)4 * HB * 2);
  float* c0 = (float*)alloc((size_t)HB * 4);
  float* c1 = (float*)alloc((size_t)HB * 4);
  float* bs = (float*)alloc((size_t)8192 * 4);
  float* di = (float*)alloc((size_t)512 * 4);

  prep_misc<<<1024, 256, 0, stream>>>(c0, c1, h0b, h1b, dout, bar, bs,
      ebih0, ebhh0, ebih1, ebhh1, dbih0, dbhh0, dbih1, dbhh1, Xdec, di);
  prep_weights<<<8192, 256, 0, stream>>>(enc0, eWih0, eWhh0, enc1, eWih1, eWhh1,
      dec0, dWhh0, dec1, dWih1, dWhh1);
  seq2seq_persist<<<NWG, 512, 0, stream>>>(Xenc, y, tfm, dWih0, fcW, fcb,
      enc0, enc1, dec0, dec1, h0b, h1b, c0, c1, bs, di, dout, bar);
}